// Round 5
// baseline (437.540 us; speedup 1.0000x reference)
//
#include <hip/hip_runtime.h>
#include <math.h>

#define NB 32
#define CIN 32
#define DIM 32
#define KK 5
#define VALID 17
#define CVOL (VALID*VALID*VALID)   // 4913
#define RSS 40                     // slab row stride in shorts (pad 2 left, aligned b64 reads)
#define ROWSL 43                   // rows 0..42; real data rows 2..33, rest stay zero
#define PLANES 11
#define SLABS (PLANES*ROWSL*RSS)   // 18920 shorts = 37840 B -> 4 blocks/CU

// ws layout (floats): [0,4000) w_eff ; [4000] B ; [4096, 4096+nsplit*NB*CVOL) C partials

__device__ __forceinline__ unsigned short f2bf(float f) {   // RNE f32->bf16
    unsigned int u = __float_as_uint(f);
    u += 0x7FFFu + ((u >> 16) & 1u);
    return (unsigned short)(u >> 16);
}
__device__ __forceinline__ float bflo(unsigned int u) { return __uint_as_float(u << 16); }
__device__ __forceinline__ float bfhi(unsigned int u) { return __uint_as_float(u & 0xFFFF0000u); }

__global__ __launch_bounds__(256) void prep_kernel(const float* __restrict__ weight,
                                                   const float* __restrict__ bias,
                                                   float* __restrict__ ws) {
    int idx = blockIdx.x * 256 + threadIdx.x;
    if (idx < 4000) {
        float s = 0.f;
        #pragma unroll 8
        for (int co = 0; co < 64; ++co) s += weight[co * 4000 + idx];
        ws[idx] = s;
    }
    if (idx == 0) {
        float b = 0.f;
        for (int i = 0; i < 64; ++i) b += bias[i];
        ws[4000] = b;
    }
}

// Block = (split s, n, d-quad q). 192 threads; dq=tid/45, h4=(tid%45)/9, wq0=tid%9.
// Thread: d = 4q+dq, h = 4*h4+hh (hh 0..3), w = 2wq, 2wq+1, wq=(wq0+h4+dq)%9.
// Slab bf16: [plane 11][row 43][RSS 40]; plane p = id 2*d0-2+p; row = ih+2; short = iw+2.
__global__ __launch_bounds__(192, 3) void conv_kernel(const float* __restrict__ x,
                                                      const float* __restrict__ weff,
                                                      float* __restrict__ C,
                                                      int cpS) {
    __shared__ unsigned short slabS[SLABS];
    const int b = blockIdx.x;
    const int s = b / (NB * 5);
    const int rem = b - s * (NB * 5);
    const int n = rem / 5;
    const int q = rem - n * 5;
    const int d0 = 4 * q;
    const int tid = threadIdx.x;

    const int dq  = tid / 45;
    const int r45 = tid - dq * 45;
    const int h4  = r45 / 9;
    const int wq0 = r45 - h4 * 9;
    const int wq  = (wq0 + h4 + dq) % 9;
    const int d   = d0 + dq;
    const bool active = (dq < 4) && (d < VALID);
    const int h0 = 4 * h4;

    // zero slab once; pads/OOB regions never rewritten
    uint4* s4 = (uint4*)slabS;
    for (int t = tid; t < SLABS / 8; t += 192) s4[t] = make_uint4(0u, 0u, 0u, 0u);
    __syncthreads();

    float acc0[4] = {0.f, 0.f, 0.f, 0.f};
    float acc1[4] = {0.f, 0.f, 0.f, 0.f};
    const int cin0 = s * cpS;

    for (int ci = 0; ci < cpS; ++ci) {
        const int cin = cin0 + ci;
        // stage one cin: 11 planes x 32x32 f32 -> bf16 slab (coalesced float4 loads)
        #pragma unroll
        for (int i = 0; i < 15; ++i) {
            int g = tid + 192 * i;
            if (g < 2816) {
                int p  = g >> 8;
                int rr = (g >> 3) & 31;
                int c4 = g & 7;
                int id = 2 * d0 - 2 + p;
                if (id >= 0 && id < DIM) {
                    const float4 v = *(const float4*)&x[((((size_t)n * CIN + cin) * DIM + id) * DIM + rr) * DIM + 4 * c4];
                    unsigned int lo = (unsigned int)f2bf(v.x) | ((unsigned int)f2bf(v.y) << 16);
                    unsigned int hi = (unsigned int)f2bf(v.z) | ((unsigned int)f2bf(v.w) << 16);
                    unsigned short* dst = &slabS[(p * ROWSL + rr + 2) * RSS + 2 + 4 * c4];
                    *(unsigned int*)dst       = lo;    // 4B-aligned ds_write_b32 x2
                    *(unsigned int*)(dst + 2) = hi;
                }
            }
        }
        __syncthreads();

        if (active) {
            const float* wb = weff + cin * 125;
            #pragma unroll
            for (int kd = 0; kd < KK; ++kd) {
                const unsigned short* plane = slabS + (2 * dq + kd) * (ROWSL * RSS);
                #pragma unroll
                for (int j = 0; j < 11; ++j) {
                    const unsigned short* row = plane + (8 * h4 + j) * RSS;
                    uint2 A  = *(const uint2*)(row + 4 * wq);       // shorts 4wq..4wq+3 (8B aligned)
                    uint2 Bv = *(const uint2*)(row + 4 * wq + 4);
                    float xm2 = bflo(A.x),  xm1 = bfhi(A.x);
                    float x0  = bflo(A.y),  xp1 = bfhi(A.y);
                    float xp2 = bflo(Bv.x), xp3 = bfhi(Bv.x);
                    float xp4 = bflo(Bv.y);
                    #pragma unroll
                    for (int hh = 0; hh < 4; ++hh) {
                        const int kh = j - 2 * hh;
                        if (kh >= 0 && kh < KK) {
                            const float w0 = wb[(kd * 5 + kh) * 5 + 0];
                            const float w1 = wb[(kd * 5 + kh) * 5 + 1];
                            const float w2 = wb[(kd * 5 + kh) * 5 + 2];
                            const float w3 = wb[(kd * 5 + kh) * 5 + 3];
                            const float w4 = wb[(kd * 5 + kh) * 5 + 4];
                            acc0[hh] = fmaf(w0, xm2, acc0[hh]);
                            acc1[hh] = fmaf(w0, x0,  acc1[hh]);
                            acc0[hh] = fmaf(w1, xm1, acc0[hh]);
                            acc1[hh] = fmaf(w1, xp1, acc1[hh]);
                            acc0[hh] = fmaf(w2, x0,  acc0[hh]);
                            acc1[hh] = fmaf(w2, xp2, acc1[hh]);
                            acc0[hh] = fmaf(w3, xp1, acc0[hh]);
                            acc1[hh] = fmaf(w3, xp3, acc1[hh]);
                            acc0[hh] = fmaf(w4, xp2, acc0[hh]);
                            acc1[hh] = fmaf(w4, xp4, acc1[hh]);
                        }
                    }
                }
            }
        }
        __syncthreads();
    }

    if (active) {
        float* Cb = C + ((size_t)s * NB + n) * CVOL + (size_t)d * (VALID * VALID);
        #pragma unroll
        for (int hh = 0; hh < 4; ++hh) {
            int h = h0 + hh;
            if (h < VALID) {
                float* Cn = Cb + h * VALID;
                int w0 = 2 * wq;
                Cn[w0] = acc0[hh];
                if (w0 + 1 < VALID) Cn[w0 + 1] = acc1[hh];
            }
        }
    }
}

// Blocks 0..863: one wave per active cell (n, i<3, j<3, k<3): lane = p1-subcell,
// fused nsplit reduction (independent pipelined loads), butterfly sum.
// Blocks 864..988: fill the 973 constant cells per n with 27*B.
__global__ __launch_bounds__(64) void pool_kernel(const float* __restrict__ C,
                                                  const float* __restrict__ wsB,
                                                  float* __restrict__ out,
                                                  int nsplit) {
    const int b = blockIdx.x;
    const int l = threadIdx.x;
    const float B = wsB[0];

    if (b < 864) {
        const int n = b / 27;
        const int cell = b - n * 27;
        const int ci = cell / 9, cj = (cell / 3) % 3, ck = cell % 3;
        float v = 0.f;
        if (l < 27) {
            const int da = l / 9, db = (l / 3) % 3, dc = l % 3;
            const int pz = 3 * ci + da, py = 3 * cj + db, px = 3 * ck + dc;
            const float* Cn = C + (size_t)n * CVOL;
            float m = -INFINITY;
            #pragma unroll
            for (int dz = 0; dz < 2; ++dz)
            #pragma unroll
            for (int dy = 0; dy < 2; ++dy)
            #pragma unroll
            for (int dx = 0; dx < 2; ++dx) {
                int z = 2 * pz + dz, y = 2 * py + dy, xx = 2 * px + dx;
                float t;
                if (z < VALID && y < VALID && xx < VALID) {
                    size_t off = ((size_t)z * VALID + y) * VALID + xx;
                    float sum = 0.f;
                    for (int ss = 0; ss < nsplit; ++ss)
                        sum += Cn[(size_t)ss * NB * CVOL + off];
                    t = sum + B;
                } else {
                    t = B;
                }
                m = fmaxf(m, t);
            }
            v = m;
        }
        #pragma unroll
        for (int off = 32; off > 0; off >>= 1) v += __shfl_xor(v, off, 64);
        if (l == 0) out[n * 1000 + ci * 100 + cj * 10 + ck] = v;
    } else {
        const int fb = b - 864;           // 0..124
        #pragma unroll
        for (int t = 0; t < 4; ++t) {
            int idx = fb * 256 + 64 * t + l;
            if (idx < 32000) {
                int r = idx % 1000;
                int i = r / 100, j = (r / 10) % 10, k = r % 10;
                if (i >= 3 || j >= 3 || k >= 3) out[idx] = 27.f * B;
            }
        }
    }
}

extern "C" void kernel_launch(void* const* d_in, const int* in_sizes, int n_in,
                              void* d_out, int out_size, void* d_ws, size_t ws_size,
                              hipStream_t stream) {
    const float* x      = (const float*)d_in[0];
    const float* weight = (const float*)d_in[1];
    const float* bias   = (const float*)d_in[2];
    float* out = (float*)d_out;
    float* ws  = (float*)d_ws;
    float* weff = ws;
    float* wsB  = ws + 4000;
    float* C    = ws + 4096;

    int nsplit = 1;
    if      (ws_size >= (size_t)(4096 + 8 * NB * CVOL) * 4) nsplit = 8;
    else if (ws_size >= (size_t)(4096 + 4 * NB * CVOL) * 4) nsplit = 4;
    else if (ws_size >= (size_t)(4096 + 2 * NB * CVOL) * 4) nsplit = 2;
    int cpS = CIN / nsplit;

    prep_kernel<<<dim3(16), dim3(256), 0, stream>>>(weight, bias, ws);
    conv_kernel<<<dim3(nsplit * NB * 5), dim3(192), 0, stream>>>(x, weff, C, cpS);
    pool_kernel<<<dim3(989), dim3(64), 0, stream>>>(C, wsB, out, nsplit);
}

// Round 6
// 143.084 us; speedup vs baseline: 3.0579x; 3.0579x over previous
//
#include <hip/hip_runtime.h>
#include <math.h>

#define NB 32
#define CIN 32
#define DIM 32
#define KK 5
#define VALID 17
#define CVOL (VALID*VALID*VALID)   // 4913
#define RS 40                      // slab row stride (words)
#define PLANES 11
#define ROWSL 43                   // sr = 8*h4 + j up to 42 (h4=4 garbage rows read zeros)
#define SLABW (PLANES*ROWSL*RS)    // 18920 words = 75680 B -> 2 blocks/CU

// ws layout (floats): [0,4000) w_eff ; [4000] B ; [4096, ...) C partials [nsplit][32][4913]

__global__ __launch_bounds__(256) void prep_kernel(const float* __restrict__ weight,
                                                   const float* __restrict__ bias,
                                                   float* __restrict__ ws) {
    int idx = blockIdx.x * 256 + threadIdx.x;
    if (idx < 4000) {
        float s = 0.f;
        #pragma unroll 8
        for (int co = 0; co < 64; ++co) s += weight[co * 4000 + idx];
        ws[idx] = s;
    }
    if (idx == 0) {
        float b = 0.f;
        for (int i = 0; i < 64; ++i) b += bias[i];
        ws[4000] = b;
    }
}

// Block = (split s, n, d-quad q). 192 threads; 180 compute-active:
// dq = tid/45, h4 = (tid%45)/9, wq0 = tid%9; wq = (wq0+h4+dq)%9.
// Thread outputs: d = 4q+dq, h = 4*h4..4*h4+3, w = 2wq, 2wq+1.
__global__ __launch_bounds__(192) void conv_kernel(const float* __restrict__ x,
                                                   const float* __restrict__ weff,
                                                   float* __restrict__ C,
                                                   int cpS) {
    __shared__ __align__(16) float slab[PLANES][ROWSL][RS];
    const int b = blockIdx.x;
    const int s = b / (NB * 5);
    const int rem = b - s * (NB * 5);
    const int n = rem / 5;
    const int q = rem - n * 5;
    const int d0 = 4 * q;
    const int tid = threadIdx.x;

    const int dq  = tid / 45;
    const int r45 = tid - dq * 45;
    const int h4  = r45 / 9;
    const int wq0 = r45 - h4 * 9;
    const int wq  = (wq0 + h4 + dq) % 9;
    const int d   = d0 + dq;
    const bool active = (dq < 4) && (d < VALID);
    const int h0 = 4 * h4;

    float4* s4 = (float4*)slab;
    for (int t = tid; t < SLABW / 4; t += 192) s4[t] = make_float4(0.f, 0.f, 0.f, 0.f);

    const int cin0 = s * cpS;
    float4 pf[15];

    {
        const int cin = cin0;
        #pragma unroll
        for (int i = 0; i < 15; ++i) {
            int g = tid + 192 * i;
            int p  = g >> 8;
            int rr = (g >> 3) & 31;
            int c4 = g & 7;
            int id = 2 * d0 - 2 + p;
            bool ok = (g < 2816) && (id >= 0) && (id < DIM);
            pf[i] = ok ? *(const float4*)&x[((((size_t)n * CIN + cin) * DIM + id) * DIM + rr) * DIM + 4 * c4]
                       : make_float4(0.f, 0.f, 0.f, 0.f);
        }
    }
    __syncthreads();

    float acc0[4] = {0.f, 0.f, 0.f, 0.f};
    float acc1[4] = {0.f, 0.f, 0.f, 0.f};

    for (int ci = 0; ci < cpS; ++ci) {
        const int cin = cin0 + ci;

        #pragma unroll
        for (int i = 0; i < 15; ++i) {
            int g = tid + 192 * i;
            if (g < 2816) {
                int p  = g >> 8;
                int rr = (g >> 3) & 31;
                int c4 = g & 7;
                float* dst = &slab[p][rr + 2][2 + 4 * c4];
                *(float2*)dst       = make_float2(pf[i].x, pf[i].y);
                *(float2*)(dst + 2) = make_float2(pf[i].z, pf[i].w);
            }
        }
        __syncthreads();

        if (ci + 1 < cpS) {
            const int cinN = cin + 1;
            #pragma unroll
            for (int i = 0; i < 15; ++i) {
                int g = tid + 192 * i;
                int p  = g >> 8;
                int rr = (g >> 3) & 31;
                int c4 = g & 7;
                int id = 2 * d0 - 2 + p;
                bool ok = (g < 2816) && (id >= 0) && (id < DIM);
                pf[i] = ok ? *(const float4*)&x[((((size_t)n * CIN + cinN) * DIM + id) * DIM + rr) * DIM + 4 * c4]
                           : make_float4(0.f, 0.f, 0.f, 0.f);
            }
        }

        if (active) {
            const float* wb = weff + cin * 125;
            #pragma unroll
            for (int kd = 0; kd < KK; ++kd) {
                const float* plane = &slab[2 * dq + kd][0][0];
                #pragma unroll
                for (int j = 0; j < 11; ++j) {
                    const int sr = 8 * h4 + j;
                    const float4* rowp = (const float4*)(plane + sr * RS);
                    float4 va = rowp[wq];
                    float4 vb = rowp[wq + 1];
                    #pragma unroll
                    for (int hh = 0; hh < 4; ++hh) {
                        const int kh = j - 2 * hh;
                        if (kh >= 0 && kh < KK) {
                            const float w0 = wb[(kd * 5 + kh) * 5 + 0];
                            const float w1 = wb[(kd * 5 + kh) * 5 + 1];
                            const float w2 = wb[(kd * 5 + kh) * 5 + 2];
                            const float w3 = wb[(kd * 5 + kh) * 5 + 3];
                            const float w4 = wb[(kd * 5 + kh) * 5 + 4];
                            acc0[hh] = fmaf(w0, va.x, acc0[hh]);
                            acc1[hh] = fmaf(w0, va.z, acc1[hh]);
                            acc0[hh] = fmaf(w1, va.y, acc0[hh]);
                            acc1[hh] = fmaf(w1, va.w, acc1[hh]);
                            acc0[hh] = fmaf(w2, va.z, acc0[hh]);
                            acc1[hh] = fmaf(w2, vb.x, acc1[hh]);
                            acc0[hh] = fmaf(w3, va.w, acc0[hh]);
                            acc1[hh] = fmaf(w3, vb.y, acc1[hh]);
                            acc0[hh] = fmaf(w4, vb.x, acc0[hh]);
                            acc1[hh] = fmaf(w4, vb.z, acc1[hh]);
                        }
                    }
                }
            }
        }
        __syncthreads();
    }

    if (active) {
        float* Cb = C + ((size_t)s * NB + n) * CVOL + (size_t)d * (VALID * VALID);
        #pragma unroll
        for (int hh = 0; hh < 4; ++hh) {
            int h = h0 + hh;
            if (h < VALID) {
                float* Cn = Cb + h * VALID;
                int w0 = 2 * wq;
                Cn[w0] = acc0[hh];
                if (w0 + 1 < VALID) Cn[w0 + 1] = acc1[hh];
            }
        }
    }
}

// Blocks 0..863: one wave per active cell (n, i<3, j<3, k<3); lane = p1-subcell;
// fused nsplit reduction; butterfly sum. Blocks 864..988: constant fill.
__global__ __launch_bounds__(64) void pool_kernel(const float* __restrict__ C,
                                                  const float* __restrict__ wsB,
                                                  float* __restrict__ out,
                                                  int nsplit) {
    const int b = blockIdx.x;
    const int l = threadIdx.x;
    const float B = wsB[0];

    if (b < 864) {
        const int n = b / 27;
        const int cell = b - n * 27;
        const int ci = cell / 9, cj = (cell / 3) % 3, ck = cell % 3;
        float v = 0.f;
        if (l < 27) {
            const int da = l / 9, db = (l / 3) % 3, dc = l % 3;
            const int pz = 3 * ci + da, py = 3 * cj + db, px = 3 * ck + dc;
            const float* Cn = C + (size_t)n * CVOL;
            float m = -INFINITY;
            #pragma unroll
            for (int dz = 0; dz < 2; ++dz)
            #pragma unroll
            for (int dy = 0; dy < 2; ++dy)
            #pragma unroll
            for (int dx = 0; dx < 2; ++dx) {
                int z = 2 * pz + dz, y = 2 * py + dy, xx = 2 * px + dx;
                float t;
                if (z < VALID && y < VALID && xx < VALID) {
                    size_t off = ((size_t)z * VALID + y) * VALID + xx;
                    float sum = 0.f;
                    for (int ss = 0; ss < nsplit; ++ss)
                        sum += Cn[(size_t)ss * NB * CVOL + off];
                    t = sum + B;
                } else {
                    t = B;
                }
                m = fmaxf(m, t);
            }
            v = m;
        }
        #pragma unroll
        for (int off = 32; off > 0; off >>= 1) v += __shfl_xor(v, off, 64);
        if (l == 0) out[n * 1000 + ci * 100 + cj * 10 + ck] = v;
    } else {
        const int fb = b - 864;           // 0..124
        #pragma unroll
        for (int t = 0; t < 4; ++t) {
            int idx = fb * 256 + 64 * t + l;
            if (idx < 32000) {
                int r = idx % 1000;
                int i = r / 100, j = (r / 10) % 10, k = r % 10;
                if (i >= 3 || j >= 3 || k >= 3) out[idx] = 27.f * B;
            }
        }
    }
}

extern "C" void kernel_launch(void* const* d_in, const int* in_sizes, int n_in,
                              void* d_out, int out_size, void* d_ws, size_t ws_size,
                              hipStream_t stream) {
    const float* x      = (const float*)d_in[0];
    const float* weight = (const float*)d_in[1];
    const float* bias   = (const float*)d_in[2];
    float* out = (float*)d_out;
    float* ws  = (float*)d_ws;
    float* weff = ws;
    float* wsB  = ws + 4000;
    float* C    = ws + 4096;

    int nsplit = 1;
    if      (ws_size >= (size_t)(4096 + 8 * NB * CVOL) * 4) nsplit = 8;
    else if (ws_size >= (size_t)(4096 + 4 * NB * CVOL) * 4) nsplit = 4;
    else if (ws_size >= (size_t)(4096 + 2 * NB * CVOL) * 4) nsplit = 2;
    int cpS = CIN / nsplit;

    prep_kernel<<<dim3(16), dim3(256), 0, stream>>>(weight, bias, ws);
    conv_kernel<<<dim3(nsplit * NB * 5), dim3(192), 0, stream>>>(x, weff, C, cpS);
    pool_kernel<<<dim3(989), dim3(64), 0, stream>>>(C, wsB, out, nsplit);
}

// Round 7
// 126.922 us; speedup vs baseline: 3.4473x; 1.1273x over previous
//
#include <hip/hip_runtime.h>
#include <math.h>

#define NB 32
#define CIN 32
#define DIM 32
#define KK 5
#define VALID 17
#define CVOL (VALID*VALID*VALID)   // 4913
#define RS 36                      // row stride (words): col = iw (0..31) + 4 right pad
#define ROWS 37                    // row = ih+2; zeros at 0,1,34,35,36
#define PLN 7                      // planes for a d-pair: ids 4p-2 .. 4p+4
#define SLABW (PLN*ROWS*RS)        // 9324 words = 37296 B -> 4 blocks/CU

// ws layout (floats): [0,4000) w_eff ; [4000] B ; [4096, ...) C partials [nsplit][32][4913]

__global__ __launch_bounds__(256) void prep_kernel(const float* __restrict__ weight,
                                                   const float* __restrict__ bias,
                                                   float* __restrict__ ws) {
    int idx = blockIdx.x * 256 + threadIdx.x;
    if (idx < 4000) {
        float s = 0.f;
        #pragma unroll 8
        for (int co = 0; co < 64; ++co) s += weight[co * 4000 + idx];
        ws[idx] = s;
    }
    if (idx == 0) {
        float b = 0.f;
        for (int i = 0; i < 64; ++i) b += bias[i];
        ws[4000] = b;
    }
}

// Block = (split s, n, d-pair p). 128 threads: dq = tid>>6 (wave), hg = (tid>>3)&7, wq = tid&7.
// Thread outputs: d = 2p+dq; h = 2hg,2hg+1 (hg=7: 14,15,16); w = 2wq+1, 2wq+2 (+ w=0 if wq==0).
// Slab: [pi 7][row 37][RS 36]; pi = id-(4p-2); row = ih+2; col = iw. kd plane: pi = 2dq+kd.
// Read quad = (37*pi + 4hg+j)*9 + wq  ==> mod 8 = const + 4hg + wq: conflict-free.
__global__ __launch_bounds__(128) void conv_kernel(const float* __restrict__ x,
                                                   const float* __restrict__ weff,
                                                   float* __restrict__ C,
                                                   int cpS) {
    __shared__ __align__(16) float slab[PLN][ROWS][RS];
    const int b = blockIdx.x;
    const int s = b / (NB * 9);
    const int rem = b - s * (NB * 9);
    const int n = rem / 9;
    const int p = rem - n * 9;
    const int tid = threadIdx.x;
    const int dq = tid >> 6;
    const int hg = (tid >> 3) & 7;
    const int wq = tid & 7;
    const int d  = 2 * p + dq;
    const bool dok = (d < VALID);
    const bool tall = (hg == 7);      // 3rd h-row
    const bool w0t  = (wq == 0);      // also computes w=0

    // zero slab once; zero rows/planes/cols never rewritten
    float4* s4 = (float4*)slab;
    for (int t = tid; t < SLABW / 4; t += 128) s4[t] = make_float4(0.f, 0.f, 0.f, 0.f);
    __syncthreads();

    const int id0 = 4 * p - 2;
    const int cin0 = s * cpS;

    float acc[3][2] = {{0.f,0.f},{0.f,0.f},{0.f,0.f}};
    float accw0[3]  = {0.f, 0.f, 0.f};

    for (int ci = 0; ci < cpS; ++ci) {
        const int cin = cin0 + ci;
        const float* xn = x + (((size_t)n * CIN + cin) * DIM) * DIM * DIM;

        // stage 7 planes (1792 float4, 14/thread), aligned ds_write_b128, conflict-free
        #pragma unroll
        for (int i = 0; i < 14; ++i) {
            int g  = tid + 128 * i;
            int pi = g >> 8;
            int rr = (g >> 3) & 31;
            int c4 = g & 7;
            int id = id0 + pi;
            if (id >= 0 && id < DIM) {
                float4 v = *(const float4*)&xn[((size_t)id * DIM + rr) * DIM + 4 * c4];
                *(float4*)&slab[pi][rr + 2][4 * c4] = v;
            }
        }
        __syncthreads();

        const float* wb = weff + cin * 125;
        #pragma unroll
        for (int kd = 0; kd < KK; ++kd) {
            const float* plane = &slab[2 * dq + kd][0][0];
            #pragma unroll
            for (int j = 0; j < 9; ++j) {
                if (j <= 6 || tall) {
                    const float* rp = plane + (4 * hg + j) * RS + 4 * wq;
                    const float4 va = *(const float4*)rp;
                    const float4 vb = *(const float4*)(rp + 4);
                    #pragma unroll
                    for (int hh = 0; hh < 3; ++hh) {
                        const int kh = j - 2 * hh;
                        if (kh >= 0 && kh < KK) {
                            if (hh < 2 || tall) {
                                const float w0 = wb[kd * 25 + kh * 5 + 0];
                                const float w1 = wb[kd * 25 + kh * 5 + 1];
                                const float w2 = wb[kd * 25 + kh * 5 + 2];
                                const float w3 = wb[kd * 25 + kh * 5 + 3];
                                const float w4 = wb[kd * 25 + kh * 5 + 4];
                                acc[hh][0] = fmaf(w0, va.x, acc[hh][0]);
                                acc[hh][1] = fmaf(w0, va.z, acc[hh][1]);
                                acc[hh][0] = fmaf(w1, va.y, acc[hh][0]);
                                acc[hh][1] = fmaf(w1, va.w, acc[hh][1]);
                                acc[hh][0] = fmaf(w2, va.z, acc[hh][0]);
                                acc[hh][1] = fmaf(w2, vb.x, acc[hh][1]);
                                acc[hh][0] = fmaf(w3, va.w, acc[hh][0]);
                                acc[hh][1] = fmaf(w3, vb.y, acc[hh][1]);
                                acc[hh][0] = fmaf(w4, vb.x, acc[hh][0]);
                                acc[hh][1] = fmaf(w4, vb.z, acc[hh][1]);
                                if (w0t) {   // w=0: iw=kw-2 >= 0 -> kw 2,3,4 -> va.x..va.z
                                    accw0[hh] = fmaf(w2, va.x, accw0[hh]);
                                    accw0[hh] = fmaf(w3, va.y, accw0[hh]);
                                    accw0[hh] = fmaf(w4, va.z, accw0[hh]);
                                }
                            }
                        }
                    }
                }
            }
        }
        __syncthreads();
    }

    if (dok) {
        float* Cn = C + ((size_t)s * NB + n) * CVOL + (size_t)d * (VALID * VALID);
        #pragma unroll
        for (int hh = 0; hh < 3; ++hh) {
            if (hh < 2 || tall) {
                int h = 2 * hg + hh;
                Cn[h * VALID + 2 * wq + 1] = acc[hh][0];
                Cn[h * VALID + 2 * wq + 2] = acc[hh][1];
                if (w0t) Cn[h * VALID] = accw0[hh];
            }
        }
    }
}

// Blocks 0..863: one wave per active cell (n, i<3, j<3, k<3); lane = p1-subcell;
// fused nsplit reduction; butterfly sum. Blocks 864..988: constant fill.
__global__ __launch_bounds__(64) void pool_kernel(const float* __restrict__ C,
                                                  const float* __restrict__ wsB,
                                                  float* __restrict__ out,
                                                  int nsplit) {
    const int b = blockIdx.x;
    const int l = threadIdx.x;
    const float B = wsB[0];

    if (b < 864) {
        const int n = b / 27;
        const int cell = b - n * 27;
        const int ci = cell / 9, cj = (cell / 3) % 3, ck = cell % 3;
        float v = 0.f;
        if (l < 27) {
            const int da = l / 9, db = (l / 3) % 3, dc = l % 3;
            const int pz = 3 * ci + da, py = 3 * cj + db, px = 3 * ck + dc;
            const float* Cn = C + (size_t)n * CVOL;
            float m = -INFINITY;
            #pragma unroll
            for (int dz = 0; dz < 2; ++dz)
            #pragma unroll
            for (int dy = 0; dy < 2; ++dy)
            #pragma unroll
            for (int dx = 0; dx < 2; ++dx) {
                int z = 2 * pz + dz, y = 2 * py + dy, xx = 2 * px + dx;
                float t;
                if (z < VALID && y < VALID && xx < VALID) {
                    size_t off = ((size_t)z * VALID + y) * VALID + xx;
                    float sum = 0.f;
                    for (int ss = 0; ss < nsplit; ++ss)
                        sum += Cn[(size_t)ss * NB * CVOL + off];
                    t = sum + B;
                } else {
                    t = B;
                }
                m = fmaxf(m, t);
            }
            v = m;
        }
        #pragma unroll
        for (int off = 32; off > 0; off >>= 1) v += __shfl_xor(v, off, 64);
        if (l == 0) out[n * 1000 + ci * 100 + cj * 10 + ck] = v;
    } else {
        const int fb = b - 864;           // 0..124
        #pragma unroll
        for (int t = 0; t < 4; ++t) {
            int idx = fb * 256 + 64 * t + l;
            if (idx < 32000) {
                int r = idx % 1000;
                int i = r / 100, j = (r / 10) % 10, k = r % 10;
                if (i >= 3 || j >= 3 || k >= 3) out[idx] = 27.f * B;
            }
        }
    }
}

extern "C" void kernel_launch(void* const* d_in, const int* in_sizes, int n_in,
                              void* d_out, int out_size, void* d_ws, size_t ws_size,
                              hipStream_t stream) {
    const float* x      = (const float*)d_in[0];
    const float* weight = (const float*)d_in[1];
    const float* bias   = (const float*)d_in[2];
    float* out = (float*)d_out;
    float* ws  = (float*)d_ws;
    float* weff = ws;
    float* wsB  = ws + 4000;
    float* C    = ws + 4096;

    int nsplit = 1;
    if      (ws_size >= (size_t)(4096 + 8 * NB * CVOL) * 4) nsplit = 8;
    else if (ws_size >= (size_t)(4096 + 4 * NB * CVOL) * 4) nsplit = 4;
    else if (ws_size >= (size_t)(4096 + 2 * NB * CVOL) * 4) nsplit = 2;
    int cpS = CIN / nsplit;

    prep_kernel<<<dim3(16), dim3(256), 0, stream>>>(weight, bias, ws);
    conv_kernel<<<dim3(nsplit * NB * 9), dim3(128), 0, stream>>>(x, weff, C, cpS);
    pool_kernel<<<dim3(989), dim3(64), 0, stream>>>(C, wsB, out, nsplit);
}

// Round 8
// 99.765 us; speedup vs baseline: 4.3857x; 1.2722x over previous
//
#include <hip/hip_runtime.h>
#include <math.h>

#define NB 32
#define CIN 32
#define DIM 32
#define KK 5
#define VALID 17
#define CVOL (VALID*VALID*VALID)   // 4913
#define RS 36                      // row stride (words): col = iw (0..31) + 4 right pad
#define ROWS 37                    // row = ih+2; zeros at 0,1,34,35,36
#define PLN 7                      // planes for a d-pair: ids 4p-2 .. 4p+4
#define SLABW (PLN*ROWS*RS)        // 9324 words = 37296 B -> 4 blocks/CU

// ws layout (floats): [0,4000) w_eff ; [4000] B ; [4096, ...) C partials [nsplit][32][4913]

__global__ __launch_bounds__(256) void prep_kernel(const float* __restrict__ weight,
                                                   const float* __restrict__ bias,
                                                   float* __restrict__ ws) {
    int idx = blockIdx.x * 256 + threadIdx.x;
    if (idx < 4000) {
        float s = 0.f;
        #pragma unroll 8
        for (int co = 0; co < 64; ++co) s += weight[co * 4000 + idx];
        ws[idx] = s;
    }
    if (idx == 0) {
        float b = 0.f;
        for (int i = 0; i < 64; ++i) b += bias[i];
        ws[4000] = b;
    }
}

// Block = (split s, n, d-pair p). 128 threads: dq = tid>>6 (wave), hg = (tid>>3)&7, wq = tid&7.
// Thread outputs: d = 2p+dq; h = 2hg,2hg+1 (hg=7: 14,15,16); w = 2wq+1, 2wq+2 (+ w=0 if wq==0).
// Slab: [pi 7][row 37][RS 36]; pi = id-(4p-2); row = ih+2; col = iw. kd plane: pi = 2dq+kd.
// Read quad = (37*pi + 4hg+j)*9 + wq  ==> mod 8 = const + 4hg + wq: conflict-free.
// T14 async-stage: next cin's 14 float4 loaded into pf[] during compute; stage = ds_writes only.
__global__ __launch_bounds__(128) void conv_kernel(const float* __restrict__ x,
                                                   const float* __restrict__ weff,
                                                   float* __restrict__ C,
                                                   int cpS) {
    __shared__ __align__(16) float slab[PLN][ROWS][RS];
    const int b = blockIdx.x;
    const int s = b / (NB * 9);
    const int rem = b - s * (NB * 9);
    const int n = rem / 9;
    const int p = rem - n * 9;
    const int tid = threadIdx.x;
    const int dq = tid >> 6;
    const int hg = (tid >> 3) & 7;
    const int wq = tid & 7;
    const int d  = 2 * p + dq;
    const bool dok = (d < VALID);
    const bool tall = (hg == 7);      // 3rd h-row
    const bool w0t  = (wq == 0);      // also computes w=0

    // zero slab once; pad rows/cols never rewritten
    float4* s4 = (float4*)slab;
    for (int t = tid; t < SLABW / 4; t += 128) s4[t] = make_float4(0.f, 0.f, 0.f, 0.f);

    const int id0 = 4 * p - 2;
    const int cin0 = s * cpS;

    // decode the 14 stage slots once
    float4 pf[14];
    {
        const float* xn = x + (((size_t)n * CIN + cin0) * DIM) * DIM * DIM;
        #pragma unroll
        for (int i = 0; i < 14; ++i) {
            int g  = tid + 128 * i;
            int pi = g >> 8;
            int rr = (g >> 3) & 31;
            int c4 = g & 7;
            int id = id0 + pi;
            bool ok = (id >= 0 && id < DIM);
            pf[i] = ok ? *(const float4*)&xn[((size_t)id * DIM + rr) * DIM + 4 * c4]
                       : make_float4(0.f, 0.f, 0.f, 0.f);
        }
    }
    __syncthreads();

    float acc[3][2] = {{0.f,0.f},{0.f,0.f},{0.f,0.f}};
    float accw0[3]  = {0.f, 0.f, 0.f};

    for (int ci = 0; ci < cpS; ++ci) {
        // stage: unconditional aligned ds_write_b128 (zeros for OOB planes), conflict-free
        #pragma unroll
        for (int i = 0; i < 14; ++i) {
            int g  = tid + 128 * i;
            int pi = g >> 8;
            int rr = (g >> 3) & 31;
            int c4 = g & 7;
            *(float4*)&slab[pi][rr + 2][4 * c4] = pf[i];
        }
        __syncthreads();

        // issue next cin's global loads; complete under compute
        if (ci + 1 < cpS) {
            const float* xn = x + (((size_t)n * CIN + cin0 + ci + 1) * DIM) * DIM * DIM;
            #pragma unroll
            for (int i = 0; i < 14; ++i) {
                int g  = tid + 128 * i;
                int pi = g >> 8;
                int rr = (g >> 3) & 31;
                int c4 = g & 7;
                int id = id0 + pi;
                bool ok = (id >= 0 && id < DIM);
                pf[i] = ok ? *(const float4*)&xn[((size_t)id * DIM + rr) * DIM + 4 * c4]
                           : make_float4(0.f, 0.f, 0.f, 0.f);
            }
        }

        const float* wb = weff + (cin0 + ci) * 125;
        #pragma unroll
        for (int kd = 0; kd < KK; ++kd) {
            const float* plane = &slab[2 * dq + kd][0][0];
            #pragma unroll
            for (int j = 0; j < 9; ++j) {
                if (j <= 6 || tall) {
                    const float* rp = plane + (4 * hg + j) * RS + 4 * wq;
                    const float4 va = *(const float4*)rp;
                    const float4 vb = *(const float4*)(rp + 4);
                    #pragma unroll
                    for (int hh = 0; hh < 3; ++hh) {
                        const int kh = j - 2 * hh;
                        if (kh >= 0 && kh < KK) {
                            if (hh < 2 || tall) {
                                const float w0 = wb[kd * 25 + kh * 5 + 0];
                                const float w1 = wb[kd * 25 + kh * 5 + 1];
                                const float w2 = wb[kd * 25 + kh * 5 + 2];
                                const float w3 = wb[kd * 25 + kh * 5 + 3];
                                const float w4 = wb[kd * 25 + kh * 5 + 4];
                                acc[hh][0] = fmaf(w0, va.x, acc[hh][0]);
                                acc[hh][1] = fmaf(w0, va.z, acc[hh][1]);
                                acc[hh][0] = fmaf(w1, va.y, acc[hh][0]);
                                acc[hh][1] = fmaf(w1, va.w, acc[hh][1]);
                                acc[hh][0] = fmaf(w2, va.z, acc[hh][0]);
                                acc[hh][1] = fmaf(w2, vb.x, acc[hh][1]);
                                acc[hh][0] = fmaf(w3, va.w, acc[hh][0]);
                                acc[hh][1] = fmaf(w3, vb.y, acc[hh][1]);
                                acc[hh][0] = fmaf(w4, vb.x, acc[hh][0]);
                                acc[hh][1] = fmaf(w4, vb.z, acc[hh][1]);
                                if (w0t) {   // w=0: kw 2,3,4 hit iw 0,1,2 -> va.x..va.z
                                    accw0[hh] = fmaf(w2, va.x, accw0[hh]);
                                    accw0[hh] = fmaf(w3, va.y, accw0[hh]);
                                    accw0[hh] = fmaf(w4, va.z, accw0[hh]);
                                }
                            }
                        }
                    }
                }
            }
        }
        __syncthreads();
    }

    if (dok) {
        float* Cn = C + ((size_t)s * NB + n) * CVOL + (size_t)d * (VALID * VALID);
        #pragma unroll
        for (int hh = 0; hh < 3; ++hh) {
            if (hh < 2 || tall) {
                int h = 2 * hg + hh;
                Cn[h * VALID + 2 * wq + 1] = acc[hh][0];
                Cn[h * VALID + 2 * wq + 2] = acc[hh][1];
                if (w0t) Cn[h * VALID] = accw0[hh];
            }
        }
    }
}

// Blocks 0..863: one wave per active cell (n, i<3, j<3, k<3); lane = p1-subcell;
// fused nsplit reduction; butterfly sum. Blocks 864..988: constant fill.
__global__ __launch_bounds__(64) void pool_kernel(const float* __restrict__ C,
                                                  const float* __restrict__ wsB,
                                                  float* __restrict__ out,
                                                  int nsplit) {
    const int b = blockIdx.x;
    const int l = threadIdx.x;
    const float B = wsB[0];

    if (b < 864) {
        const int n = b / 27;
        const int cell = b - n * 27;
        const int ci = cell / 9, cj = (cell / 3) % 3, ck = cell % 3;
        float v = 0.f;
        if (l < 27) {
            const int da = l / 9, db = (l / 3) % 3, dc = l % 3;
            const int pz = 3 * ci + da, py = 3 * cj + db, px = 3 * ck + dc;
            const float* Cn = C + (size_t)n * CVOL;
            float m = -INFINITY;
            #pragma unroll
            for (int dz = 0; dz < 2; ++dz)
            #pragma unroll
            for (int dy = 0; dy < 2; ++dy)
            #pragma unroll
            for (int dx = 0; dx < 2; ++dx) {
                int z = 2 * pz + dz, y = 2 * py + dy, xx = 2 * px + dx;
                float t;
                if (z < VALID && y < VALID && xx < VALID) {
                    size_t off = ((size_t)z * VALID + y) * VALID + xx;
                    float sum = 0.f;
                    for (int ss = 0; ss < nsplit; ++ss)
                        sum += Cn[(size_t)ss * NB * CVOL + off];
                    t = sum + B;
                } else {
                    t = B;
                }
                m = fmaxf(m, t);
            }
            v = m;
        }
        #pragma unroll
        for (int off = 32; off > 0; off >>= 1) v += __shfl_xor(v, off, 64);
        if (l == 0) out[n * 1000 + ci * 100 + cj * 10 + ck] = v;
    } else {
        const int fb = b - 864;           // 0..124
        #pragma unroll
        for (int t = 0; t < 4; ++t) {
            int idx = fb * 256 + 64 * t + l;
            if (idx < 32000) {
                int r = idx % 1000;
                int i = r / 100, j = (r / 10) % 10, k = r % 10;
                if (i >= 3 || j >= 3 || k >= 3) out[idx] = 27.f * B;
            }
        }
    }
}

extern "C" void kernel_launch(void* const* d_in, const int* in_sizes, int n_in,
                              void* d_out, int out_size, void* d_ws, size_t ws_size,
                              hipStream_t stream) {
    const float* x      = (const float*)d_in[0];
    const float* weight = (const float*)d_in[1];
    const float* bias   = (const float*)d_in[2];
    float* out = (float*)d_out;
    float* ws  = (float*)d_ws;
    float* weff = ws;
    float* wsB  = ws + 4000;
    float* C    = ws + 4096;

    int nsplit = 1;
    if      (ws_size >= (size_t)(4096 + 8 * NB * CVOL) * 4) nsplit = 8;
    else if (ws_size >= (size_t)(4096 + 4 * NB * CVOL) * 4) nsplit = 4;
    else if (ws_size >= (size_t)(4096 + 2 * NB * CVOL) * 4) nsplit = 2;
    int cpS = CIN / nsplit;

    prep_kernel<<<dim3(16), dim3(256), 0, stream>>>(weight, bias, ws);
    conv_kernel<<<dim3(nsplit * NB * 9), dim3(128), 0, stream>>>(x, weff, C, cpS);
    pool_kernel<<<dim3(989), dim3(64), 0, stream>>>(C, wsB, out, nsplit);
}